// Round 2
// baseline (766.819 us; speedup 1.0000x reference)
//
#include <hip/hip_runtime.h>
#include <math.h>

using u16 = unsigned short;
using u32 = unsigned int;

typedef __attribute__((ext_vector_type(4))) float f32x4;
typedef __attribute__((ext_vector_type(8))) short s16x8;

__device__ __forceinline__ u16 f2bf(float f) {
  union { float f; u32 u; } c; c.f = f;
  u32 u = c.u;
  u += 0x7fffu + ((u >> 16) & 1u);   // round-to-nearest-even
  return (u16)(u >> 16);
}
__device__ __forceinline__ float bf2f(u16 s) {
  union { u32 u; float f; } c; c.u = ((u32)s) << 16;
  return c.f;
}

// ---------------- LayerNorm: rows x 256 f32 -> bf16, one wave per row ----------------
__global__ __launch_bounds__(256) void ln_kernel(
    const float* __restrict__ x, const float* __restrict__ sc,
    const float* __restrict__ bi, u16* __restrict__ out) {
  const int w = threadIdx.x >> 6, l = threadIdx.x & 63;
  const int row = blockIdx.x * 4 + w;
  const float4 v = ((const float4*)(x + (size_t)row * 256))[l];
  float s  = v.x + v.y + v.z + v.w;
  float s2 = v.x * v.x + v.y * v.y + v.z * v.z + v.w * v.w;
#pragma unroll
  for (int m = 1; m < 64; m <<= 1) {
    s  += __shfl_xor(s,  m, 64);
    s2 += __shfl_xor(s2, m, 64);
  }
  const float mean = s * (1.0f / 256.0f);
  const float var  = s2 * (1.0f / 256.0f) - mean * mean;
  const float rs   = rsqrtf(var + 1e-5f);
  const float4 s4 = ((const float4*)sc)[l];
  const float4 b4 = ((const float4*)bi)[l];
  u16 o0 = f2bf((v.x - mean) * rs * s4.x + b4.x);
  u16 o1 = f2bf((v.y - mean) * rs * s4.y + b4.y);
  u16 o2 = f2bf((v.z - mean) * rs * s4.z + b4.z);
  u16 o3 = f2bf((v.w - mean) * rs * s4.w + b4.w);
  uint2 p; p.x = (u32)o0 | ((u32)o1 << 16); p.y = (u32)o2 | ((u32)o3 << 16);
  *(uint2*)(out + (size_t)row * 256 + l * 4) = p;
}

// ---------------- weight convert f32 [K][N] -> bf16 transposed [N][K] ----------------
__global__ __launch_bounds__(256) void convw_kernel(
    const float* s0, const float* s1, const float* s2, const float* s3,
    const float* s4, const float* s5,
    u16* d0, u16* d1, u16* d2, u16* d3, u16* d4, u16* d5) {
  const float* s; u16* d; int K, N, sh;
  switch (blockIdx.y) {
    case 0: s = s0; d = d0; K = 256; N = 256; sh = 8; break;  // Wq
    case 1: s = s1; d = d1; K = 256; N = 256; sh = 8; break;  // Wgate -> rows 256..511 of WQGT
    case 2: s = s2; d = d2; K = 256; N = 512; sh = 9; break;  // Wkv
    case 3: s = s3; d = d3; K = 256; N = 256; sh = 8; break;  // Wout
    case 4: s = s4; d = d4; K = 256; N = 512; sh = 9; break;  // W1
    default: s = s5; d = d5; K = 512; N = 256; sh = 8; break; // W2
  }
  const int idx = blockIdx.x * 256 + threadIdx.x;
  if (idx >= K * N) return;
  const int k = idx >> sh, n = idx & (N - 1);
  d[(size_t)n * K + k] = f2bf(s[idx]);
}

// ---------------- V transpose: KV v-part -> VT[n][h][c][j] (j contiguous) ----------------
__global__ __launch_bounds__(256) void vtrans_kernel(const u16* __restrict__ KV,
                                                     u16* __restrict__ VT) {
  const int n = blockIdx.x, h = blockIdx.y;
  const int t = threadIdx.x;
  const int j = t >> 2, cg = t & 3;
  union { uint4 v; u16 u[8]; } d;
  d.v = *(const uint4*)(KV + ((size_t)(j * 384 + n)) * 512 + 256 + h * 32 + cg * 8);
  u16* dst = VT + (((size_t)n * 8 + h) * 32 + cg * 8) * 64 + j;
#pragma unroll
  for (int c = 0; c < 8; c++) dst[c * 64] = d.u[c];
}

// ---------------- streaming GEMM, K=256, no LDS, no barriers ----------------
// C[M][N] = A[M][256] @ W, BT = W^T [N][256]. 128x128 tile, 4 waves 2x2.
// Fragments straight from global (B is L2-resident weights; A L2/L3 re-read).
// epi: 0 = store bf16; 2 = f32 res + acc*rmask
__global__ __launch_bounds__(256) void gemm256(
    const u16* __restrict__ A, const u16* __restrict__ BT, const int N,
    u16* __restrict__ outb, float* __restrict__ outf,
    const float* __restrict__ res, const int* __restrict__ rmask, const int epi) {
  const int t = threadIdx.x, w = t >> 6, l = t & 63;
  const int lm = l & 15, lk = l >> 4;
  const int mb = blockIdx.y * 128, nb = blockIdx.x * 128;
  const int m0 = (w >> 1) * 64, n0 = (w & 1) * 64;

  const u16* aP = A  + (size_t)(mb + m0 + lm) * 256 + lk * 8;
  const u16* bP = BT + (size_t)(nb + n0 + lm) * 256 + lk * 8;

  f32x4 acc[4][4] = {};
  s16x8 a[2][4], b[2][4];
#pragma unroll
  for (int i = 0; i < 4; i++) {
    a[0][i] = *(const s16x8*)(aP + i * 16 * 256);
    b[0][i] = *(const s16x8*)(bP + i * 16 * 256);
  }
#pragma unroll
  for (int kc = 0; kc < 8; kc++) {
    const int cur = kc & 1, nxt = cur ^ 1;
    if (kc < 7) {
#pragma unroll
      for (int i = 0; i < 4; i++) {
        a[nxt][i] = *(const s16x8*)(aP + i * 16 * 256 + (kc + 1) * 32);
        b[nxt][i] = *(const s16x8*)(bP + i * 16 * 256 + (kc + 1) * 32);
      }
    }
#pragma unroll
    for (int i = 0; i < 4; i++)
#pragma unroll
      for (int j = 0; j < 4; j++)
        acc[i][j] = __builtin_amdgcn_mfma_f32_16x16x32_bf16(a[cur][i], b[cur][j], acc[i][j], 0, 0, 0);
  }

  const int r0 = mb + m0 + lk * 4;
  const int c0 = nb + n0 + lm;
  if (epi == 0) {
#pragma unroll
    for (int i = 0; i < 4; i++)
#pragma unroll
      for (int j = 0; j < 4; j++)
#pragma unroll
        for (int r = 0; r < 4; r++)
          outb[(size_t)(r0 + i * 16 + r) * N + (c0 + j * 16)] = f2bf(acc[i][j][r]);
  } else {
#pragma unroll
    for (int i = 0; i < 4; i++)
#pragma unroll
      for (int r = 0; r < 4; r++) {
        const int row = r0 + i * 16 + r;
        const float rm = (float)rmask[row];
#pragma unroll
        for (int j = 0; j < 4; j++) {
          const size_t idx = (size_t)row * N + (c0 + j * 16);
          outf[idx] = res[idx] + acc[i][j][r] * rm;
        }
      }
  }
}

// ---------------- fused FFN: out = x + (relu(lnx@W1+b1)@W2 + b2) * rmask ----------------
// block: 128 rows x 128 out-cols; h (128x512) recomputed per col-block in 128-col chunks,
// round-tripped through 32 KB LDS (XOR-chunk layout, conflict-free b128 reads).
__global__ __launch_bounds__(256) void ffn_kernel(
    const u16* __restrict__ lnx, const u16* __restrict__ W1T,
    const u16* __restrict__ W2T, const float* __restrict__ b1,
    const float* __restrict__ b2, const float* __restrict__ x,
    const int* __restrict__ rmask, float* __restrict__ out) {
  __shared__ u16 hbuf[4 * 128 * 32];   // 4 k-chunks of [128 rows][32 elems]
  const int t = threadIdx.x, w = t >> 6, l = t & 63;
  const int lm = l & 15, lk = l >> 4;
  const int rb = blockIdx.y * 128, cb = blockIdx.x * 128;
  const int m0 = (w >> 1) * 64, n0 = (w & 1) * 64;

  const u16* aP = lnx + (size_t)(rb + m0 + lm) * 256 + lk * 8;

  f32x4 acc[4][4] = {};
  const f32x4 zz = {0.f, 0.f, 0.f, 0.f};

  for (int nc = 0; nc < 4; nc++) {
    // ---- phase A: h-chunk = relu(lnx @ W1[:, nc*128 + ...] + b1) ----
    f32x4 ah[4][4];
#pragma unroll
    for (int i = 0; i < 4; i++)
#pragma unroll
      for (int j = 0; j < 4; j++) ah[i][j] = zz;
    const u16* b1P = W1T + (size_t)(nc * 128 + n0 + lm) * 256 + lk * 8;
#pragma unroll
    for (int kc = 0; kc < 8; kc++) {
      s16x8 a[4], b[4];
#pragma unroll
      for (int i = 0; i < 4; i++) {
        a[i] = *(const s16x8*)(aP + i * 16 * 256 + kc * 32);
        b[i] = *(const s16x8*)(b1P + i * 16 * 256 + kc * 32);
      }
#pragma unroll
      for (int i = 0; i < 4; i++)
#pragma unroll
        for (int j = 0; j < 4; j++)
          ah[i][j] = __builtin_amdgcn_mfma_f32_16x16x32_bf16(a[i], b[j], ah[i][j], 0, 0, 0);
    }
    if (nc) __syncthreads();   // phase-B readers of previous chunk done
    // relu + bias, store to hbuf: h(row r, col c) -> [c>>5][r][ ((c>>3)&3)^((r>>1)&3) ][c&7]
#pragma unroll
    for (int j = 0; j < 4; j++) {
      const int c = n0 + j * 16 + lm;
      const float bv = b1[nc * 128 + c];
      const int kc2 = c >> 5, lc = (c >> 3) & 3, c7 = c & 7;
#pragma unroll
      for (int i = 0; i < 4; i++)
#pragma unroll
        for (int r = 0; r < 4; r++) {
          const int row = m0 + i * 16 + lk * 4 + r;
          const float v = fmaxf(ah[i][j][r] + bv, 0.0f);
          hbuf[kc2 * 4096 + row * 32 + ((lc ^ ((row >> 1) & 3)) << 3) + c7] = f2bf(v);
        }
    }
    __syncthreads();
    // ---- phase B: acc += h_chunk @ W2[nc*128 + ..., cb..] ----
    const u16* b2P = W2T + (size_t)(cb + n0 + lm) * 512 + nc * 128 + lk * 8;
#pragma unroll
    for (int kc = 0; kc < 4; kc++) {
      s16x8 a[4], b[4];
#pragma unroll
      for (int i = 0; i < 4; i++) {
        const int row = m0 + i * 16 + lm;
        a[i] = *(const s16x8*)&hbuf[kc * 4096 + row * 32 + ((lk ^ ((row >> 1) & 3)) << 3)];
        b[i] = *(const s16x8*)(b2P + i * 16 * 512 + kc * 32);
      }
#pragma unroll
      for (int i = 0; i < 4; i++)
#pragma unroll
        for (int j = 0; j < 4; j++)
          acc[i][j] = __builtin_amdgcn_mfma_f32_16x16x32_bf16(a[i], b[j], acc[i][j], 0, 0, 0);
    }
  }

  // epilogue: out = x + (acc + b2) * rmask
  const int r0 = rb + m0 + lk * 4;
  const int c0 = cb + n0 + lm;
#pragma unroll
  for (int i = 0; i < 4; i++)
#pragma unroll
    for (int r = 0; r < 4; r++) {
      const int row = r0 + i * 16 + r;
      const float rm = (float)rmask[row];
#pragma unroll
      for (int j = 0; j < 4; j++) {
        const int col = c0 + j * 16;
        const size_t idx = (size_t)row * 256 + col;
        out[idx] = x[idx] + (acc[i][j][r] + b2[col]) * rm;
      }
    }
}

// ---------------- attention: softmax over HEADS (axis=-1 of bijnh!), mask cancels ----------------
__global__ __launch_bounds__(256) void attn_kernel(
    const u16* __restrict__ QG, const u16* __restrict__ KV,
    const u16* __restrict__ VT, u16* __restrict__ O) {
  __shared__ u16 P[8][16][72];   // [h][i][j], pad 64->72 to kill read bank conflicts
  const int n = blockIdx.x, ig = blockIdx.y;
  const int t = threadIdx.x, w = t >> 6, l = t & 63;
  const int lm = l & 15, lk = l >> 4;

  const u16* qb = QG + ((size_t)(ig * 16 + lm) * 384 + n) * 512 + lk * 8;
  const u16* kb = KV + ((size_t)(w * 16 + lm) * 384 + n) * 512 + lk * 8;
  const f32x4 zz = {0.f, 0.f, 0.f, 0.f};
  f32x4 acc[8];
#pragma unroll
  for (int h = 0; h < 8; h++) {
    s16x8 af = *(const s16x8*)(qb + h * 32);
    s16x8 bf = *(const s16x8*)(kb + h * 32);
    acc[h] = __builtin_amdgcn_mfma_f32_16x16x32_bf16(af, bf, zz, 0, 0, 0);
  }
#pragma unroll
  for (int r = 0; r < 4; r++) {
    float mx = acc[0][r];
#pragma unroll
    for (int h = 1; h < 8; h++) mx = fmaxf(mx, acc[h][r]);
    float e[8], s = 0.f;
#pragma unroll
    for (int h = 0; h < 8; h++) { e[h] = __expf(acc[h][r] - mx); s += e[h]; }
    const float inv = 1.0f / s;
#pragma unroll
    for (int h = 0; h < 8; h++) P[h][lk * 4 + r][w * 16 + lm] = f2bf(e[h] * inv);
  }
  __syncthreads();

  const u16* vb = VT + ((size_t)n * 8) * 2048;   // [h][c 32][j 64]
#pragma unroll
  for (int hh = 0; hh < 2; hh++) {
    const int h = w * 2 + hh;
#pragma unroll
    for (int nt = 0; nt < 2; nt++) {
      f32x4 o = zz;
#pragma unroll
      for (int ks = 0; ks < 2; ks++) {
        s16x8 af = *(const s16x8*)&P[h][lm][ks * 32 + lk * 8];
        s16x8 bf = *(const s16x8*)(vb + (size_t)h * 2048 + (nt * 16 + lm) * 64 + ks * 32 + lk * 8);
        o = __builtin_amdgcn_mfma_f32_16x16x32_bf16(af, bf, o, 0, 0, 0);
      }
#pragma unroll
      for (int r = 0; r < 4; r++) {
        const int i = ig * 16 + lk * 4 + r;
        const int col = h * 32 + nt * 16 + lm;
        const size_t orow = (size_t)i * 384 + n;
        const float g = bf2f(QG[orow * 512 + 256 + col]);
        const float val = o[r] / (1.0f + __expf(-g));   // out * sigmoid(gate)
        O[orow * 256 + col] = f2bf(val);
      }
    }
  }
}

extern "C" void kernel_launch(void* const* d_in, const int* in_sizes, int n_in,
                              void* d_out, int out_size, void* d_ws, size_t ws_size,
                              hipStream_t stream) {
  (void)in_sizes; (void)n_in; (void)out_size; (void)ws_size;
  const float* embed  = (const float*)d_in[0];
  const float* memory = (const float*)d_in[1];
  const int*   rmask  = (const int*)d_in[2];
  // d_in[3] memory_mask: provably no effect (softmax over h cancels the bias)
  const float* lnqs = (const float*)d_in[4];
  const float* lnqb = (const float*)d_in[5];
  const float* lnks = (const float*)d_in[6];
  const float* lnkb = (const float*)d_in[7];
  const float* Wq   = (const float*)d_in[8];
  const float* Wkv  = (const float*)d_in[9];
  const float* Wg   = (const float*)d_in[10];
  const float* Wo   = (const float*)d_in[11];
  const float* lnfs = (const float*)d_in[12];
  const float* lnfb = (const float*)d_in[13];
  const float* W1   = (const float*)d_in[14];
  const float* b1   = (const float*)d_in[15];
  const float* W2   = (const float*)d_in[16];
  const float* b2   = (const float*)d_in[17];
  float* out = (float*)d_out;
  char* ws = (char*)d_ws;

  // workspace layout (peak ~240.3 MB, with aliasing)
  u16* qe   = (u16*)(ws + 0);              // 98304x256 bf16
  u16* km   = (u16*)(ws + 50331648);       // 24576x256 bf16
  u16* VT   = km;                          // aliases km (dead after KV GEMM)
  u16* QG   = (u16*)(ws + 62914560);       // 98304x512 bf16 (q | gate)
  u16* KV   = (u16*)(ws + 163577856);      // 24576x512 bf16 (k | v)
  u16* O    = (u16*)(ws + 188743680);      // 98304x256 bf16 gated attn out
  u16* WQGT = (u16*)(ws + 239075328);      // [512][256]
  u16* WKVT = WQGT + 131072;               // [512][256]
  u16* WOUTT= WKVT + 131072;               // [256][256]
  u16* W1T  = WOUTT + 65536;               // [512][256]
  u16* W2T  = W1T + 131072;                // [256][512]
  u16* lnx  = qe;                          // aliases qe (dead after QG GEMM)

  convw_kernel<<<dim3(512, 6), 256, 0, stream>>>(Wq, Wg, Wkv, Wo, W1, W2,
      WQGT, WQGT + 65536, WKVT, WOUTT, W1T, W2T);
  ln_kernel<<<24576, 256, 0, stream>>>(embed, lnqs, lnqb, qe);
  ln_kernel<<<6144, 256, 0, stream>>>(memory, lnks, lnkb, km);
  gemm256<<<dim3(4, 768), 256, 0, stream>>>(qe, WQGT, 512, QG, nullptr, nullptr, nullptr, 0);
  gemm256<<<dim3(4, 192), 256, 0, stream>>>(km, WKVT, 512, KV, nullptr, nullptr, nullptr, 0);
  vtrans_kernel<<<dim3(384, 8), 256, 0, stream>>>(KV, VT);
  attn_kernel<<<dim3(384, 16), 256, 0, stream>>>(QG, KV, VT, O);
  gemm256<<<dim3(2, 768), 256, 0, stream>>>(O, WOUTT, 256, nullptr, out, embed, rmask, 2);
  ln_kernel<<<24576, 256, 0, stream>>>(out, lnfs, lnfb, lnx);
  ffn_kernel<<<dim3(2, 768), 256, 0, stream>>>(lnx, W1T, W2T, b1, b2, out, rmask, out);
}

// Round 3
// 667.738 us; speedup vs baseline: 1.1484x; 1.1484x over previous
//
#include <hip/hip_runtime.h>
#include <math.h>

using u16 = unsigned short;
using u32 = unsigned int;

typedef __attribute__((ext_vector_type(4))) float f32x4;
typedef __attribute__((ext_vector_type(8))) short s16x8;

__device__ __forceinline__ u16 f2bf(float f) {
  union { float f; u32 u; } c; c.f = f;
  u32 u = c.u;
  u += 0x7fffu + ((u >> 16) & 1u);   // round-to-nearest-even
  return (u16)(u >> 16);
}
__device__ __forceinline__ float bf2f(u16 s) {
  union { u32 u; float f; } c; c.u = ((u32)s) << 16;
  return c.f;
}

// barrier WITHOUT vmcnt(0) drain: LDS visibility only; global prefetches stay in flight
#define BAR() do { asm volatile("s_waitcnt lgkmcnt(0)" ::: "memory"); \
                   __builtin_amdgcn_s_barrier(); } while (0)

// ---------------- LayerNorm: rows x 256 f32 -> bf16, one wave per row ----------------
__global__ __launch_bounds__(256) void ln_kernel(
    const float* __restrict__ x, const float* __restrict__ sc,
    const float* __restrict__ bi, u16* __restrict__ out) {
  const int w = threadIdx.x >> 6, l = threadIdx.x & 63;
  const int row = blockIdx.x * 4 + w;
  const float4 v = ((const float4*)(x + (size_t)row * 256))[l];
  float s  = v.x + v.y + v.z + v.w;
  float s2 = v.x * v.x + v.y * v.y + v.z * v.z + v.w * v.w;
#pragma unroll
  for (int m = 1; m < 64; m <<= 1) {
    s  += __shfl_xor(s,  m, 64);
    s2 += __shfl_xor(s2, m, 64);
  }
  const float mean = s * (1.0f / 256.0f);
  const float var  = s2 * (1.0f / 256.0f) - mean * mean;
  const float rs   = rsqrtf(var + 1e-5f);
  const float4 s4 = ((const float4*)sc)[l];
  const float4 b4 = ((const float4*)bi)[l];
  u16 o0 = f2bf((v.x - mean) * rs * s4.x + b4.x);
  u16 o1 = f2bf((v.y - mean) * rs * s4.y + b4.y);
  u16 o2 = f2bf((v.z - mean) * rs * s4.z + b4.z);
  u16 o3 = f2bf((v.w - mean) * rs * s4.w + b4.w);
  uint2 p; p.x = (u32)o0 | ((u32)o1 << 16); p.y = (u32)o2 | ((u32)o3 << 16);
  *(uint2*)(out + (size_t)row * 256 + l * 4) = p;
}

// ---------------- weight convert f32 [K][N] -> bf16 transposed [N][K] ----------------
__global__ __launch_bounds__(256) void convw_kernel(
    const float* s0, const float* s1, const float* s2, const float* s3,
    const float* s4, const float* s5,
    u16* d0, u16* d1, u16* d2, u16* d3, u16* d4, u16* d5) {
  const float* s; u16* d; int K, N, sh;
  switch (blockIdx.y) {
    case 0: s = s0; d = d0; K = 256; N = 256; sh = 8; break;  // Wq
    case 1: s = s1; d = d1; K = 256; N = 256; sh = 8; break;  // Wgate -> rows 256..511 of WQGT
    case 2: s = s2; d = d2; K = 256; N = 512; sh = 9; break;  // Wkv
    case 3: s = s3; d = d3; K = 256; N = 256; sh = 8; break;  // Wout
    case 4: s = s4; d = d4; K = 256; N = 512; sh = 9; break;  // W1
    default: s = s5; d = d5; K = 512; N = 256; sh = 8; break; // W2
  }
  const int idx = blockIdx.x * 256 + threadIdx.x;
  if (idx >= K * N) return;
  const int k = idx >> sh, n = idx & (N - 1);
  d[(size_t)n * K + k] = f2bf(s[idx]);
}

// ---------------- V transpose: KV v-part -> VT[n][h][c][j] (j contiguous) ----------------
__global__ __launch_bounds__(256) void vtrans_kernel(const u16* __restrict__ KV,
                                                     u16* __restrict__ VT) {
  const int n = blockIdx.x, h = blockIdx.y;
  const int t = threadIdx.x;
  const int j = t >> 2, cg = t & 3;
  union { uint4 v; u16 u[8]; } d;
  d.v = *(const uint4*)(KV + ((size_t)(j * 384 + n)) * 512 + 256 + h * 32 + cg * 8);
  u16* dst = VT + (((size_t)n * 8 + h) * 32 + cg * 8) * 64 + j;
#pragma unroll
  for (int c = 0; c < 8; c++) dst[c * 64] = d.u[c];
}

// ---------------- GEMM v3: 128x128 tile, BK=32, VGPR-staged 2-deep prefetch ----------------
// Loads for iter k+2 issued at iter k, held in VGPRs, ds_write at iter k+2; barriers are
// lgkmcnt-only so global loads stay in flight across them (no vmcnt(0) drain).
// epi: 0 = store bf16; 1 = bf16(relu(acc+bias)); 2 = f32 res+acc*rmask; 3 = f32 out+=(acc+bias)*rmask
__global__ __launch_bounds__(256) void gemm_v3(
    const u16* __restrict__ A, const u16* __restrict__ BT,
    const int K, const int N,
    u16* __restrict__ outb, float* __restrict__ outf,
    const float* __restrict__ bias, const float* __restrict__ res,
    const int* __restrict__ rmask, const int epi) {
  __shared__ u16 Als[128 * 32];
  __shared__ u16 Bls[128 * 32];
  const int t = threadIdx.x, w = t >> 6, l = t & 63;
  const int lm = l & 15, lk = l >> 4;
  const int mb = blockIdx.y * 128, nb = blockIdx.x * 128;
  const int m0 = (w >> 1) * 64, n0 = (w & 1) * 64;

  // staging: wave w owns rows w*32..w*32+31 of both tiles (two 16-row halves)
  const int srow = l >> 2;                       // 0..15
  const int scg  = (l & 3) ^ ((srow >> 1) & 3);  // swizzled global 16B-chunk
  const u16* gA = A  + (size_t)(mb + w * 32 + srow) * K + scg * 8;
  const u16* gB = BT + (size_t)(nb + w * 32 + srow) * K + scg * 8;
  const size_t rk16 = (size_t)16 * K;
  u16* wA0 = &Als[w * 1024 + l * 8];             // == (w*32+srow)*32 + (l&3)*8
  u16* wA1 = wA0 + 16 * 32;
  u16* wB0 = &Bls[w * 1024 + l * 8];
  u16* wB1 = wB0 + 16 * 32;

  const int pc = (lk ^ ((lm >> 1) & 3)) * 8;     // swizzled read chunk (elements)
  f32x4 acc[4][4] = {};

  // prologue: prefetch iters 0 and 1 into registers
  uint4 a00 = *(const uint4*)gA;
  uint4 a01 = *(const uint4*)(gA + rk16);
  uint4 b00 = *(const uint4*)gB;
  uint4 b01 = *(const uint4*)(gB + rk16);
  uint4 a10 = *(const uint4*)(gA + 32);
  uint4 a11 = *(const uint4*)(gA + rk16 + 32);
  uint4 b10 = *(const uint4*)(gB + 32);
  uint4 b11 = *(const uint4*)(gB + rk16 + 32);

  const int NI = K >> 5;   // 8 or 16, always even
  for (int it = 0; it < NI; it += 2) {
    // ---- even iter: data in set0 ----
    *(uint4*)wA0 = a00; *(uint4*)wA1 = a01;
    *(uint4*)wB0 = b00; *(uint4*)wB1 = b01;
    BAR();
    if (it + 2 < NI) {
      a00 = *(const uint4*)(gA + (it + 2) * 32);
      a01 = *(const uint4*)(gA + rk16 + (it + 2) * 32);
      b00 = *(const uint4*)(gB + (it + 2) * 32);
      b01 = *(const uint4*)(gB + rk16 + (it + 2) * 32);
    }
    {
      s16x8 af[4], bf[4];
#pragma unroll
      for (int i = 0; i < 4; i++) af[i] = *(const s16x8*)&Als[(m0 + i * 16 + lm) * 32 + pc];
#pragma unroll
      for (int j = 0; j < 4; j++) bf[j] = *(const s16x8*)&Bls[(n0 + j * 16 + lm) * 32 + pc];
#pragma unroll
      for (int i = 0; i < 4; i++)
#pragma unroll
        for (int j = 0; j < 4; j++)
          acc[i][j] = __builtin_amdgcn_mfma_f32_16x16x32_bf16(af[i], bf[j], acc[i][j], 0, 0, 0);
    }
    BAR();
    // ---- odd iter: data in set1 ----
    *(uint4*)wA0 = a10; *(uint4*)wA1 = a11;
    *(uint4*)wB0 = b10; *(uint4*)wB1 = b11;
    BAR();
    if (it + 3 < NI) {
      a10 = *(const uint4*)(gA + (it + 3) * 32);
      a11 = *(const uint4*)(gA + rk16 + (it + 3) * 32);
      b10 = *(const uint4*)(gB + (it + 3) * 32);
      b11 = *(const uint4*)(gB + rk16 + (it + 3) * 32);
    }
    {
      s16x8 af[4], bf[4];
#pragma unroll
      for (int i = 0; i < 4; i++) af[i] = *(const s16x8*)&Als[(m0 + i * 16 + lm) * 32 + pc];
#pragma unroll
      for (int j = 0; j < 4; j++) bf[j] = *(const s16x8*)&Bls[(n0 + j * 16 + lm) * 32 + pc];
#pragma unroll
      for (int i = 0; i < 4; i++)
#pragma unroll
        for (int j = 0; j < 4; j++)
          acc[i][j] = __builtin_amdgcn_mfma_f32_16x16x32_bf16(af[i], bf[j], acc[i][j], 0, 0, 0);
    }
    BAR();
  }

  const int r0 = mb + m0 + lk * 4;
  const int c0 = nb + n0 + lm;
  if (epi == 0) {
#pragma unroll
    for (int i = 0; i < 4; i++)
#pragma unroll
      for (int j = 0; j < 4; j++)
#pragma unroll
        for (int r = 0; r < 4; r++)
          outb[(size_t)(r0 + i * 16 + r) * N + (c0 + j * 16)] = f2bf(acc[i][j][r]);
  } else if (epi == 1) {
#pragma unroll
    for (int i = 0; i < 4; i++)
#pragma unroll
      for (int j = 0; j < 4; j++)
#pragma unroll
        for (int r = 0; r < 4; r++) {
          const int col = c0 + j * 16;
          const float v = fmaxf(acc[i][j][r] + bias[col], 0.0f);
          outb[(size_t)(r0 + i * 16 + r) * N + col] = f2bf(v);
        }
  } else if (epi == 2) {
#pragma unroll
    for (int i = 0; i < 4; i++)
#pragma unroll
      for (int r = 0; r < 4; r++) {
        const int row = r0 + i * 16 + r;
        const float rm = (float)rmask[row];
#pragma unroll
        for (int j = 0; j < 4; j++) {
          const size_t idx = (size_t)row * N + (c0 + j * 16);
          outf[idx] = res[idx] + acc[i][j][r] * rm;
        }
      }
  } else {
#pragma unroll
    for (int i = 0; i < 4; i++)
#pragma unroll
      for (int r = 0; r < 4; r++) {
        const int row = r0 + i * 16 + r;
        const float rm = (float)rmask[row];
#pragma unroll
        for (int j = 0; j < 4; j++) {
          const int col = c0 + j * 16;
          const size_t idx = (size_t)row * N + col;
          outf[idx] = outf[idx] + (acc[i][j][r] + bias[col]) * rm;
        }
      }
  }
}

// ---------------- attention: softmax over HEADS (axis=-1 of bijnh!), mask cancels ----------------
// v3: gate preloaded to LDS (coalesced 16B), O staged in LDS, coalesced 16B writeout.
__global__ __launch_bounds__(256) void attn_kernel(
    const u16* __restrict__ QG, const u16* __restrict__ KV,
    const u16* __restrict__ VT, u16* __restrict__ O) {
  __shared__ u16 P[8][16][72];     // [h][i][j], pad 64->72
  __shared__ u16 Gld[16][264];     // gate tile, pad 256->264
  __shared__ u16 Old[16][264];     // out tile
  const int n = blockIdx.x, ig = blockIdx.y;
  const int t = threadIdx.x, w = t >> 6, l = t & 63;
  const int lm = l & 15, lk = l >> 4;

  // preload gate tile (consumed after the P barrier; latency hidden by QK^T)
#pragma unroll
  for (int itg = 0; itg < 2; itg++) {
    const int idx = itg * 256 + t;
    const int r = idx >> 5, ch = idx & 31;
    uint4 g = *(const uint4*)(QG + ((size_t)(ig * 16 + r) * 384 + n) * 512 + 256 + ch * 8);
    *(uint4*)&Gld[r][ch * 8] = g;
  }

  const u16* qb = QG + ((size_t)(ig * 16 + lm) * 384 + n) * 512 + lk * 8;
  const u16* kb = KV + ((size_t)(w * 16 + lm) * 384 + n) * 512 + lk * 8;
  const f32x4 zz = {0.f, 0.f, 0.f, 0.f};
  f32x4 acc[8];
#pragma unroll
  for (int h = 0; h < 8; h++) {
    s16x8 af = *(const s16x8*)(qb + h * 32);
    s16x8 bf = *(const s16x8*)(kb + h * 32);
    acc[h] = __builtin_amdgcn_mfma_f32_16x16x32_bf16(af, bf, zz, 0, 0, 0);
  }
#pragma unroll
  for (int r = 0; r < 4; r++) {
    float mx = acc[0][r];
#pragma unroll
    for (int h = 1; h < 8; h++) mx = fmaxf(mx, acc[h][r]);
    float e[8], s = 0.f;
#pragma unroll
    for (int h = 0; h < 8; h++) { e[h] = __expf(acc[h][r] - mx); s += e[h]; }
    const float inv = 1.0f / s;
#pragma unroll
    for (int h = 0; h < 8; h++) P[h][lk * 4 + r][w * 16 + lm] = f2bf(e[h] * inv);
  }
  __syncthreads();

  const u16* vb = VT + ((size_t)n * 8) * 2048;   // [h][c 32][j 64]
#pragma unroll
  for (int hh = 0; hh < 2; hh++) {
    const int h = w * 2 + hh;
#pragma unroll
    for (int nt = 0; nt < 2; nt++) {
      f32x4 o = zz;
#pragma unroll
      for (int ks = 0; ks < 2; ks++) {
        s16x8 af = *(const s16x8*)&P[h][lm][ks * 32 + lk * 8];
        s16x8 bf = *(const s16x8*)(vb + (size_t)h * 2048 + (nt * 16 + lm) * 64 + ks * 32 + lk * 8);
        o = __builtin_amdgcn_mfma_f32_16x16x32_bf16(af, bf, o, 0, 0, 0);
      }
#pragma unroll
      for (int r = 0; r < 4; r++) {
        const int row = lk * 4 + r;
        const int col = h * 32 + nt * 16 + lm;
        const float g = bf2f(Gld[row][col]);
        Old[row][col] = f2bf(o[r] / (1.0f + __expf(-g)));   // out * sigmoid(gate)
      }
    }
  }
  __syncthreads();
  // coalesced writeout: 16 rows x 512 B
#pragma unroll
  for (int itg = 0; itg < 2; itg++) {
    const int idx = itg * 256 + t;
    const int r = idx >> 5, ch = idx & 31;
    uint4 val = *(const uint4*)&Old[r][ch * 8];
    *(uint4*)(O + ((size_t)(ig * 16 + r) * 384 + n) * 256 + ch * 8) = val;
  }
}

extern "C" void kernel_launch(void* const* d_in, const int* in_sizes, int n_in,
                              void* d_out, int out_size, void* d_ws, size_t ws_size,
                              hipStream_t stream) {
  (void)in_sizes; (void)n_in; (void)out_size; (void)ws_size;
  const float* embed  = (const float*)d_in[0];
  const float* memory = (const float*)d_in[1];
  const int*   rmask  = (const int*)d_in[2];
  // d_in[3] memory_mask: provably no effect (softmax over h cancels the bias)
  const float* lnqs = (const float*)d_in[4];
  const float* lnqb = (const float*)d_in[5];
  const float* lnks = (const float*)d_in[6];
  const float* lnkb = (const float*)d_in[7];
  const float* Wq   = (const float*)d_in[8];
  const float* Wkv  = (const float*)d_in[9];
  const float* Wg   = (const float*)d_in[10];
  const float* Wo   = (const float*)d_in[11];
  const float* lnfs = (const float*)d_in[12];
  const float* lnfb = (const float*)d_in[13];
  const float* W1   = (const float*)d_in[14];
  const float* b1   = (const float*)d_in[15];
  const float* W2   = (const float*)d_in[16];
  const float* b2   = (const float*)d_in[17];
  float* out = (float*)d_out;
  char* ws = (char*)d_ws;

  // workspace layout (peak ~240.3 MB, with aliasing)
  u16* qe   = (u16*)(ws + 0);              // 98304x256 bf16
  u16* km   = (u16*)(ws + 50331648);       // 24576x256 bf16
  u16* VT   = km;                          // aliases km (dead after KV GEMM)
  u16* QG   = (u16*)(ws + 62914560);       // 98304x512 bf16 (q | gate)
  u16* h1   = QG;                          // aliases QG (dead after attention)
  u16* KV   = (u16*)(ws + 163577856);      // 24576x512 bf16 (k | v)
  u16* O    = (u16*)(ws + 188743680);      // 98304x256 bf16 gated attn out
  u16* WQGT = (u16*)(ws + 239075328);      // [512][256]
  u16* WKVT = WQGT + 131072;               // [512][256]
  u16* WOUTT= WKVT + 131072;               // [256][256]
  u16* W1T  = WOUTT + 65536;               // [512][256]
  u16* W2T  = W1T + 131072;                // [256][512]
  u16* lnx  = qe;                          // aliases qe (dead after QG GEMM)

  convw_kernel<<<dim3(512, 6), 256, 0, stream>>>(Wq, Wg, Wkv, Wo, W1, W2,
      WQGT, WQGT + 65536, WKVT, WOUTT, W1T, W2T);
  ln_kernel<<<24576, 256, 0, stream>>>(embed, lnqs, lnqb, qe);
  ln_kernel<<<6144, 256, 0, stream>>>(memory, lnks, lnkb, km);
  gemm_v3<<<dim3(4, 768), 256, 0, stream>>>(qe, WQGT, 256, 512, QG, nullptr, nullptr, nullptr, nullptr, 0);
  gemm_v3<<<dim3(4, 192), 256, 0, stream>>>(km, WKVT, 256, 512, KV, nullptr, nullptr, nullptr, nullptr, 0);
  vtrans_kernel<<<dim3(384, 8), 256, 0, stream>>>(KV, VT);
  attn_kernel<<<dim3(384, 16), 256, 0, stream>>>(QG, KV, VT, O);
  gemm_v3<<<dim3(2, 768), 256, 0, stream>>>(O, WOUTT, 256, 256, nullptr, out, nullptr, embed, rmask, 2);
  ln_kernel<<<24576, 256, 0, stream>>>(out, lnfs, lnfb, lnx);
  gemm_v3<<<dim3(4, 768), 256, 0, stream>>>(lnx, W1T, 256, 512, h1, nullptr, b1, nullptr, nullptr, 1);
  gemm_v3<<<dim3(2, 768), 256, 0, stream>>>(h1, W2T, 512, 256, nullptr, out, b2, nullptr, rmask, 3);
}